// Round 1
// baseline (928.120 us; speedup 1.0000x reference)
//
#include <hip/hip_runtime.h>
#include <math.h>

#define DMODEL 512
#define NHEADS 8
#define NEXP 4
#define SEQ 1024
#define BATCH 4
#define NTOK 4096  // BATCH * SEQ

__device__ __forceinline__ float dev_sigmoid(float x) { return 1.0f / (1.0f + expf(-x)); }
__device__ __forceinline__ float dev_silu(float x) { return x / (1.0f + expf(-x)); }
__device__ __forceinline__ float dev_softplus(float x) {
  return x > 0.0f ? x + log1pf(expf(-x)) : log1pf(expf(x));
}

// ---------------- zero kernel (core accumulator must start at 0; ws is poisoned 0xAA) ----
__global__ __launch_bounds__(256) void zero_kernel(float4* __restrict__ p) {
  p[(size_t)blockIdx.x * 256 + threadIdx.x] = make_float4(0.f, 0.f, 0.f, 0.f);
}

// ---------------- router + beta/g small projections: one wave per token ----------------
__global__ __launch_bounds__(64) void router_kernel(
    const float* __restrict__ h, const float* __restrict__ Wb,
    const float* __restrict__ Wa, const float* __restrict__ Wgate,
    const float* __restrict__ A_log, const float* __restrict__ dt_bias,
    float* __restrict__ beta_o, float* __restrict__ g_o, float* __restrict__ w_o) {
  const int t = blockIdx.x;
  const int lane = threadIdx.x;
  float hv[8];
#pragma unroll
  for (int j = 0; j < 8; ++j) hv[j] = h[(size_t)t * DMODEL + j * 64 + lane];
  float db[8], da[8], dg[4];
#pragma unroll
  for (int c = 0; c < 8; ++c) {
    float s1 = 0.f, s2 = 0.f;
#pragma unroll
    for (int j = 0; j < 8; ++j) {
      int row = j * 64 + lane;
      s1 += hv[j] * Wb[row * NHEADS + c];
      s2 += hv[j] * Wa[row * NHEADS + c];
    }
#pragma unroll
    for (int off = 1; off < 64; off <<= 1) {
      s1 += __shfl_xor(s1, off);
      s2 += __shfl_xor(s2, off);
    }
    db[c] = s1; da[c] = s2;
  }
#pragma unroll
  for (int c = 0; c < 4; ++c) {
    float s = 0.f;
#pragma unroll
    for (int j = 0; j < 8; ++j) s += hv[j] * Wgate[(j * 64 + lane) * NEXP + c];
#pragma unroll
    for (int off = 1; off < 64; off <<= 1) s += __shfl_xor(s, off);
    dg[c] = s;
  }
  if (lane == 0) {
#pragma unroll
    for (int c = 0; c < 8; ++c) {
      beta_o[t * NHEADS + c] = dev_sigmoid(db[c]);
      g_o[t * NHEADS + c] = -expf(A_log[c]) * dev_softplus(da[c] + dt_bias[c]);
    }
    // softmax over 4 experts (max-subtracted, like jax.nn.softmax)
    float mx = fmaxf(fmaxf(dg[0], dg[1]), fmaxf(dg[2], dg[3]));
    float p[4]; float sum = 0.f;
#pragma unroll
    for (int c = 0; c < 4; ++c) { p[c] = expf(dg[c] - mx); sum += p[c]; }
#pragma unroll
    for (int c = 0; c < 4; ++c) p[c] /= sum;
    // top-2, first-occurrence tie-break (matches jax.lax.top_k)
    float v1 = -1e30f; int i1 = 0;
#pragma unroll
    for (int c = 0; c < 4; ++c) { if (p[c] > v1) { v1 = p[c]; i1 = c; } }
    float v2 = -1e30f; int i2 = -1;
#pragma unroll
    for (int c = 0; c < 4; ++c) { if (c != i1 && p[c] > v2) { v2 = p[c]; i2 = c; } }
    float s2v = v1 + v2;
#pragma unroll
    for (int c = 0; c < 4; ++c) {
      float wv = 0.f;
      if (c == i1) wv = v1 / s2v;
      else if (c == i2) wv = v2 / s2v;
      w_o[t * NEXP + c] = wv;
    }
  }
}

// ---------------- fp32 tiled GEMM: C[M,512] = A[M,512] @ B[512,512] -----------------
// MODE 0: plain   MODE 1: silu   MODE 2: silu + per-64-col-head l2norm
template <int MODE>
__global__ __launch_bounds__(256) void gemm512(
    const float* __restrict__ A, const float* __restrict__ B,
    float* __restrict__ C) {
  constexpr int N = DMODEL, K = DMODEL;
  __shared__ float As[32][68];  // [k][m], padded
  __shared__ float Bs[32][68];  // [k][n], padded
  const int tid = threadIdx.x;
  const int tx = tid & 15, ty = tid >> 4;
  const int m0 = blockIdx.x * 64, n0 = blockIdx.y * 64;
  const int ar = tid >> 3, ak = (tid & 7) * 4;
  const int bk = tid >> 4, bn = (tid & 15) * 4;
  float acc[4][4] = {};
  for (int kk = 0; kk < K; kk += 32) {
    float4 a0 = *(const float4*)&A[(size_t)(m0 + ar) * K + kk + ak];
    float4 a1 = *(const float4*)&A[(size_t)(m0 + ar + 32) * K + kk + ak];
    float4 b0 = *(const float4*)&B[(size_t)(kk + bk) * N + n0 + bn];
    float4 b1 = *(const float4*)&B[(size_t)(kk + bk + 16) * N + n0 + bn];
    __syncthreads();
    As[ak + 0][ar] = a0.x; As[ak + 1][ar] = a0.y; As[ak + 2][ar] = a0.z; As[ak + 3][ar] = a0.w;
    As[ak + 0][ar + 32] = a1.x; As[ak + 1][ar + 32] = a1.y; As[ak + 2][ar + 32] = a1.z; As[ak + 3][ar + 32] = a1.w;
    *(float4*)&Bs[bk][bn] = b0;
    *(float4*)&Bs[bk + 16][bn] = b1;
    __syncthreads();
#pragma unroll
    for (int kq = 0; kq < 32; ++kq) {
      float4 a4 = *(const float4*)&As[kq][ty * 4];
      float4 b4 = *(const float4*)&Bs[kq][tx * 4];
      float av[4] = {a4.x, a4.y, a4.z, a4.w};
      float bv[4] = {b4.x, b4.y, b4.z, b4.w};
#pragma unroll
      for (int i = 0; i < 4; ++i)
#pragma unroll
        for (int j = 0; j < 4; ++j) acc[i][j] = fmaf(av[i], bv[j], acc[i][j]);
    }
  }
  if (MODE == 0) {
#pragma unroll
    for (int i = 0; i < 4; ++i) {
      float4 v4 = make_float4(acc[i][0], acc[i][1], acc[i][2], acc[i][3]);
      *(float4*)&C[(size_t)(m0 + ty * 4 + i) * N + n0 + tx * 4] = v4;
    }
  } else {
    float s[4][4];
#pragma unroll
    for (int i = 0; i < 4; ++i)
#pragma unroll
      for (int j = 0; j < 4; ++j) s[i][j] = dev_silu(acc[i][j]);
    if (MODE == 2) {
      // l2norm over the 64 cols of this head (tile == head): reduce across the 16 tx lanes
      float ss[4];
#pragma unroll
      for (int i = 0; i < 4; ++i)
        ss[i] = s[i][0] * s[i][0] + s[i][1] * s[i][1] + s[i][2] * s[i][2] + s[i][3] * s[i][3];
#pragma unroll
      for (int off = 1; off < 16; off <<= 1) {
#pragma unroll
        for (int i = 0; i < 4; ++i) ss[i] += __shfl_xor(ss[i], off);
      }
#pragma unroll
      for (int i = 0; i < 4; ++i) {
        float rn = 1.0f / sqrtf(ss[i] + 1e-6f);
#pragma unroll
        for (int j = 0; j < 4; ++j) s[i][j] *= rn;
      }
    }
#pragma unroll
    for (int i = 0; i < 4; ++i) {
      float4 v4 = make_float4(s[i][0], s[i][1], s[i][2], s[i][3]);
      *(float4*)&C[(size_t)(m0 + ty * 4 + i) * N + n0 + tx * 4] = v4;
    }
  }
}

// ---------------- gated delta-rule scan: one wave per (e,b,h), lane = DV column ---------
__global__ __launch_bounds__(64) void scan_kernel(
    const float* __restrict__ qb, const float* __restrict__ kb,
    const float* __restrict__ vb, const float* __restrict__ betab,
    const float* __restrict__ gbuf, const float* __restrict__ wbuf,
    float* __restrict__ coreb) {
  const int e = blockIdx.x, b = blockIdx.y, hh = blockIdx.z;
  const int lane = threadIdx.x;
  float S[64];  // state column S[k][lane], k = 0..63
#pragma unroll
  for (int i = 0; i < 64; ++i) S[i] = 0.f;
  __shared__ __align__(16) float lk[64];
  __shared__ __align__(16) float lq[64];
  for (int l = 0; l < SEQ; ++l) {
    const int t = b * SEQ + l;
    const float we = wbuf[t * NEXP + e];
    if (we > 0.f) {  // uniform across the wave; non-routed => beta=0,g=0 => S unchanged
      const size_t base = (size_t)t * DMODEL + hh * 64 + lane;
      const float qv = qb[base];
      const float kvl = kb[base];
      const float vv = vb[base];
      const float gv = gbuf[t * NHEADS + hh];
      const float bt = betab[t * NHEADS + hh];
      const float eg = expf(gv);
      __syncthreads();
      lk[lane] = kvl;
      lq[lane] = qv;
      __syncthreads();
      float c0 = 0.f, c1 = 0.f, c2 = 0.f, c3 = 0.f;
#pragma unroll
      for (int j = 0; j < 16; ++j) {
        const float4 k4 = *(const float4*)&lk[j * 4];
        float s0 = S[4 * j + 0] * eg; S[4 * j + 0] = s0; c0 = fmaf(k4.x, s0, c0);
        float s1 = S[4 * j + 1] * eg; S[4 * j + 1] = s1; c1 = fmaf(k4.y, s1, c1);
        float s2 = S[4 * j + 2] * eg; S[4 * j + 2] = s2; c2 = fmaf(k4.z, s2, c2);
        float s3 = S[4 * j + 3] * eg; S[4 * j + 3] = s3; c3 = fmaf(k4.w, s3, c3);
      }
      const float delta = (vv - (c0 + c1 + c2 + c3)) * bt;
      float o0 = 0.f, o1 = 0.f, o2 = 0.f, o3 = 0.f;
#pragma unroll
      for (int j = 0; j < 16; ++j) {
        const float4 k4 = *(const float4*)&lk[j * 4];
        const float4 q4 = *(const float4*)&lq[j * 4];
        float s0 = fmaf(k4.x, delta, S[4 * j + 0]); S[4 * j + 0] = s0; o0 = fmaf(q4.x, s0, o0);
        float s1 = fmaf(k4.y, delta, S[4 * j + 1]); S[4 * j + 1] = s1; o1 = fmaf(q4.y, s1, o1);
        float s2 = fmaf(k4.z, delta, S[4 * j + 2]); S[4 * j + 2] = s2; o2 = fmaf(q4.z, s2, o2);
        float s3 = fmaf(k4.w, delta, S[4 * j + 3]); S[4 * j + 3] = s3; o3 = fmaf(q4.w, s3, o3);
      }
      const float ov = (o0 + o1 + o2 + o3) * 0.125f * we;  // scale = DK^-0.5, weighted combine
      atomicAdd(&coreb[base], ov);
    }
  }
}

// ---------------- fused gated RMSNorm: one wave per (token, head) ----------------
__global__ __launch_bounds__(512) void rmsnorm_kernel(
    const float* __restrict__ coreb, const float* __restrict__ gateb,
    const float* __restrict__ wn, float* __restrict__ outb) {
  const int t = blockIdx.x;
  const int tid = threadIdx.x;  // 512 = 8 heads * 64; wave == head
  const int v = tid & 63;
  const float x = coreb[(size_t)t * DMODEL + tid];
  float ss = x * x;
#pragma unroll
  for (int off = 1; off < 64; off <<= 1) ss += __shfl_xor(ss, off);
  const float r = rsqrtf(ss * (1.0f / 64.0f) + 1e-5f);
  const float gt = gateb[(size_t)t * DMODEL + tid];  // already silu'd
  outb[(size_t)t * DMODEL + tid] = x * r * wn[v] * gt;
}

extern "C" void kernel_launch(void* const* d_in, const int* in_sizes, int n_in,
                              void* d_out, int out_size, void* d_ws, size_t ws_size,
                              hipStream_t stream) {
  const float* h       = (const float*)d_in[0];
  const float* Wq      = (const float*)d_in[1];
  const float* Wgate   = (const float*)d_in[2];
  const float* Wk      = (const float*)d_in[3];
  const float* Wv      = (const float*)d_in[4];
  const float* Wb      = (const float*)d_in[5];
  const float* Wa      = (const float*)d_in[6];
  const float* A_log   = (const float*)d_in[7];
  const float* dt_bias = (const float*)d_in[8];
  const float* Wg      = (const float*)d_in[9];
  const float* wn      = (const float*)d_in[10];
  const float* Wo      = (const float*)d_in[11];
  float* out = (float*)d_out;

  float* ws = (float*)d_ws;
  const size_t big = (size_t)NTOK * DMODEL;  // 2M floats
  float* qb    = ws;
  float* kb    = qb + big;
  float* vb    = kb + big;
  float* gateb = vb + big;
  float* coreb = gateb + big;
  float* betab = coreb + big;
  float* gbuf  = betab + (size_t)NTOK * NHEADS;
  float* wbuf  = gbuf + (size_t)NTOK * NHEADS;
  float* normb = qb;  // reuse q buffer after the scan

  // zero the core accumulator (ws is poisoned before every timed launch)
  zero_kernel<<<dim3(NTOK * DMODEL / 4 / 256), 256, 0, stream>>>((float4*)coreb);

  router_kernel<<<dim3(NTOK), 64, 0, stream>>>(h, Wb, Wa, Wgate, A_log, dt_bias,
                                               betab, gbuf, wbuf);

  dim3 gg(NTOK / 64, DMODEL / 64);
  gemm512<2><<<gg, 256, 0, stream>>>(h, Wq, qb);
  gemm512<2><<<gg, 256, 0, stream>>>(h, Wk, kb);
  gemm512<1><<<gg, 256, 0, stream>>>(h, Wv, vb);
  gemm512<1><<<gg, 256, 0, stream>>>(h, Wg, gateb);

  scan_kernel<<<dim3(NEXP, BATCH, NHEADS), 64, 0, stream>>>(qb, kb, vb, betab, gbuf,
                                                            wbuf, coreb);

  rmsnorm_kernel<<<dim3(NTOK), 512, 0, stream>>>(coreb, gateb, wn, normb);

  gemm512<0><<<gg, 256, 0, stream>>>(normb, Wo, out);
}

// Round 2
// 745.871 us; speedup vs baseline: 1.2443x; 1.2443x over previous
//
#include <hip/hip_runtime.h>
#include <math.h>

#define DMODEL 512
#define NHEADS 8
#define NEXP 4
#define SEQ 1024
#define BATCH 4
#define NTOK 4096  // BATCH * SEQ

__device__ __forceinline__ float dev_sigmoid(float x) { return 1.0f / (1.0f + expf(-x)); }
__device__ __forceinline__ float dev_silu(float x) { return x / (1.0f + expf(-x)); }
__device__ __forceinline__ float dev_softplus(float x) {
  return x > 0.0f ? x + log1pf(expf(-x)) : log1pf(expf(x));
}
__device__ __forceinline__ float2 f2fma(float2 a, float2 b, float2 c) {
  return make_float2(fmaf(a.x, b.x, c.x), fmaf(a.y, b.y, c.y));
}
__device__ __forceinline__ float2 f2mul(float2 a, float2 b) {
  return make_float2(a.x * b.x, a.y * b.y);
}
__device__ __forceinline__ float2 f2add(float2 a, float2 b) {
  return make_float2(a.x + b.x, a.y + b.y);
}

// ---------------- zero kernel (core accumulator must start at 0; ws is poisoned 0xAA) ----
__global__ __launch_bounds__(256) void zero_kernel(float4* __restrict__ p) {
  p[(size_t)blockIdx.x * 256 + threadIdx.x] = make_float4(0.f, 0.f, 0.f, 0.f);
}

// ---------------- router + beta/g small projections: one wave per token ----------------
__global__ __launch_bounds__(64) void router_kernel(
    const float* __restrict__ h, const float* __restrict__ Wb,
    const float* __restrict__ Wa, const float* __restrict__ Wgate,
    const float* __restrict__ A_log, const float* __restrict__ dt_bias,
    float* __restrict__ beta_o, float* __restrict__ g_o, float* __restrict__ w_o) {
  const int t = blockIdx.x;
  const int lane = threadIdx.x;
  float hv[8];
#pragma unroll
  for (int j = 0; j < 8; ++j) hv[j] = h[(size_t)t * DMODEL + j * 64 + lane];
  float db[8], da[8], dg[4];
#pragma unroll
  for (int c = 0; c < 8; ++c) {
    float s1 = 0.f, s2 = 0.f;
#pragma unroll
    for (int j = 0; j < 8; ++j) {
      int row = j * 64 + lane;
      s1 += hv[j] * Wb[row * NHEADS + c];
      s2 += hv[j] * Wa[row * NHEADS + c];
    }
#pragma unroll
    for (int off = 1; off < 64; off <<= 1) {
      s1 += __shfl_xor(s1, off);
      s2 += __shfl_xor(s2, off);
    }
    db[c] = s1; da[c] = s2;
  }
#pragma unroll
  for (int c = 0; c < 4; ++c) {
    float s = 0.f;
#pragma unroll
    for (int j = 0; j < 8; ++j) s += hv[j] * Wgate[(j * 64 + lane) * NEXP + c];
#pragma unroll
    for (int off = 1; off < 64; off <<= 1) s += __shfl_xor(s, off);
    dg[c] = s;
  }
  if (lane == 0) {
#pragma unroll
    for (int c = 0; c < 8; ++c) {
      beta_o[t * NHEADS + c] = dev_sigmoid(db[c]);
      g_o[t * NHEADS + c] = -expf(A_log[c]) * dev_softplus(da[c] + dt_bias[c]);
    }
    // softmax over 4 experts (max-subtracted, like jax.nn.softmax)
    float mx = fmaxf(fmaxf(dg[0], dg[1]), fmaxf(dg[2], dg[3]));
    float p[4]; float sum = 0.f;
#pragma unroll
    for (int c = 0; c < 4; ++c) { p[c] = expf(dg[c] - mx); sum += p[c]; }
#pragma unroll
    for (int c = 0; c < 4; ++c) p[c] /= sum;
    // top-2, first-occurrence tie-break (matches jax.lax.top_k)
    float v1 = -1e30f; int i1 = 0;
#pragma unroll
    for (int c = 0; c < 4; ++c) { if (p[c] > v1) { v1 = p[c]; i1 = c; } }
    float v2 = -1e30f; int i2 = -1;
#pragma unroll
    for (int c = 0; c < 4; ++c) { if (c != i1 && p[c] > v2) { v2 = p[c]; i2 = c; } }
    float s2v = v1 + v2;
#pragma unroll
    for (int c = 0; c < 4; ++c) {
      float wv = 0.f;
      if (c == i1) wv = v1 / s2v;
      else if (c == i2) wv = v2 / s2v;
      w_o[t * NEXP + c] = wv;
    }
  }
}

// ---------------- routed-token compaction: one wave per (e,b) ----------------
__global__ __launch_bounds__(64) void compact_kernel(
    const float* __restrict__ wbuf, int* __restrict__ tidx, int* __restrict__ tcnt) {
  const int e = blockIdx.x, b = blockIdx.y;
  const int lane = threadIdx.x;
  int* out = tidx + (e * BATCH + b) * SEQ;
  int cnt = 0;
  for (int g0 = 0; g0 < SEQ; g0 += 64) {
    const int l = g0 + lane;
    const float w = wbuf[(b * SEQ + l) * NEXP + e];
    const unsigned long long m = __ballot(w > 0.f);
    const int pos = __popcll(m & ((1ull << lane) - 1ull));
    if (w > 0.f) out[cnt + pos] = l;
    cnt += __popcll(m);
  }
  if (lane == 0) tcnt[e * BATCH + b] = cnt;
}

// ---------------- fp32 tiled GEMM: C[M,512] = A[M,512] @ B[512,512] -----------------
// MODE 0: plain   MODE 1: silu   MODE 2: silu + per-64-col-head l2norm
template <int MODE>
__global__ __launch_bounds__(256) void gemm512(
    const float* __restrict__ A, const float* __restrict__ B,
    float* __restrict__ C) {
  constexpr int N = DMODEL, K = DMODEL;
  __shared__ float As[32][68];  // [k][m], padded
  __shared__ float Bs[32][68];  // [k][n], padded
  const int tid = threadIdx.x;
  const int tx = tid & 15, ty = tid >> 4;
  const int m0 = blockIdx.x * 64, n0 = blockIdx.y * 64;
  const int ar = tid >> 3, ak = (tid & 7) * 4;
  const int bk = tid >> 4, bn = (tid & 15) * 4;
  float acc[4][4] = {};
  for (int kk = 0; kk < K; kk += 32) {
    float4 a0 = *(const float4*)&A[(size_t)(m0 + ar) * K + kk + ak];
    float4 a1 = *(const float4*)&A[(size_t)(m0 + ar + 32) * K + kk + ak];
    float4 b0 = *(const float4*)&B[(size_t)(kk + bk) * N + n0 + bn];
    float4 b1 = *(const float4*)&B[(size_t)(kk + bk + 16) * N + n0 + bn];
    __syncthreads();
    As[ak + 0][ar] = a0.x; As[ak + 1][ar] = a0.y; As[ak + 2][ar] = a0.z; As[ak + 3][ar] = a0.w;
    As[ak + 0][ar + 32] = a1.x; As[ak + 1][ar + 32] = a1.y; As[ak + 2][ar + 32] = a1.z; As[ak + 3][ar + 32] = a1.w;
    *(float4*)&Bs[bk][bn] = b0;
    *(float4*)&Bs[bk + 16][bn] = b1;
    __syncthreads();
#pragma unroll
    for (int kq = 0; kq < 32; ++kq) {
      float4 a4 = *(const float4*)&As[kq][ty * 4];
      float4 b4 = *(const float4*)&Bs[kq][tx * 4];
      float av[4] = {a4.x, a4.y, a4.z, a4.w};
      float bv[4] = {b4.x, b4.y, b4.z, b4.w};
#pragma unroll
      for (int i = 0; i < 4; ++i)
#pragma unroll
        for (int j = 0; j < 4; ++j) acc[i][j] = fmaf(av[i], bv[j], acc[i][j]);
    }
  }
  if (MODE == 0) {
#pragma unroll
    for (int i = 0; i < 4; ++i) {
      float4 v4 = make_float4(acc[i][0], acc[i][1], acc[i][2], acc[i][3]);
      *(float4*)&C[(size_t)(m0 + ty * 4 + i) * N + n0 + tx * 4] = v4;
    }
  } else {
    float s[4][4];
#pragma unroll
    for (int i = 0; i < 4; ++i)
#pragma unroll
      for (int j = 0; j < 4; ++j) s[i][j] = dev_silu(acc[i][j]);
    if (MODE == 2) {
      // l2norm over the 64 cols of this head (tile == head): reduce across the 16 tx lanes
      float ss[4];
#pragma unroll
      for (int i = 0; i < 4; ++i)
        ss[i] = s[i][0] * s[i][0] + s[i][1] * s[i][1] + s[i][2] * s[i][2] + s[i][3] * s[i][3];
#pragma unroll
      for (int off = 1; off < 16; off <<= 1) {
#pragma unroll
        for (int i = 0; i < 4; ++i) ss[i] += __shfl_xor(ss[i], off);
      }
#pragma unroll
      for (int i = 0; i < 4; ++i) {
        float rn = 1.0f / sqrtf(ss[i] + 1e-6f);
#pragma unroll
        for (int j = 0; j < 4; ++j) s[i][j] *= rn;
      }
    }
#pragma unroll
    for (int i = 0; i < 4; ++i) {
      float4 v4 = make_float4(s[i][0], s[i][1], s[i][2], s[i][3]);
      *(float4*)&C[(size_t)(m0 + ty * 4 + i) * N + n0 + tx * 4] = v4;
    }
  }
}

// ---------------- gated delta-rule scan ----------------
// grid (NEXP*2, BATCH, NHEADS); one wave per block.
// vhalf = blockIdx.x&1 selects 32 of the 64 v-columns; within the wave,
// lane = (kh, vi): kh = lane>>5 picks the k-half, vi = lane&31 the column.
// Per-lane state: S[kh*32 .. kh*32+31][vhalf*32+vi] = 32 floats (16 float2).
// Compact token list (no branch) + depth-1 prefetch + double-buffered LDS
// broadcast of k/q; k kept in registers between the two passes.
__global__ __launch_bounds__(64) void scan_kernel(
    const float* __restrict__ qb, const float* __restrict__ kb,
    const float* __restrict__ vb, const float* __restrict__ betab,
    const float* __restrict__ gbuf, const float* __restrict__ wbuf,
    const int* __restrict__ tidx, const int* __restrict__ tcnt,
    float* __restrict__ coreb) {
  const int vhalf = blockIdx.x & 1, e = blockIdx.x >> 1;
  const int b = blockIdx.y, hh = blockIdx.z;
  const int lane = threadIdx.x;
  const int kh = lane >> 5;
  const int vi = lane & 31;
  const int cv = vhalf * 32 + vi;
  const int* idx = tidx + (e * BATCH + b) * SEQ;
  const int n = tcnt[e * BATCH + b];
  __shared__ __align__(16) float lk[2][64];
  __shared__ __align__(16) float lq[2][64];
  float2 S2[16];
#pragma unroll
  for (int j = 0; j < 16; ++j) S2[j] = make_float2(0.f, 0.f);
  if (n == 0) return;

  // prologue: load + stage step 0
  int t0 = b * SEQ + idx[0];
  {
    const size_t kq0 = (size_t)t0 * DMODEL + hh * 64 + lane;
    const size_t v0 = (size_t)t0 * DMODEL + hh * 64 + cv;
    float kr = kb[kq0], qr = qb[kq0];
    lk[0][lane] = kr; lq[0][lane] = qr;
  }
  float vv = vb[(size_t)t0 * DMODEL + hh * 64 + cv];
  float egc = expf(gbuf[t0 * NHEADS + hh]);
  float bt = betab[t0 * NHEADS + hh];
  float we = wbuf[t0 * NEXP + e];
  int t_cur = t0;
  int l_nxt = idx[(1 < n) ? 1 : 0];

  for (int i = 0; i < n; ++i) {
    const int cur = i & 1, nxt = cur ^ 1;
    // ---- issue prefetch for step i+1 (addresses independent of state) ----
    const int tn = b * SEQ + l_nxt;
    const size_t kqn = (size_t)tn * DMODEL + hh * 64 + lane;
    const float kreg_n = kb[kqn];
    const float qreg_n = qb[kqn];
    const float vv_n = vb[(size_t)tn * DMODEL + hh * 64 + cv];
    const float gv_n = gbuf[tn * NHEADS + hh];
    const float bt_n = betab[tn * NHEADS + hh];
    const float we_n = wbuf[tn * NEXP + e];
    const int l_nn = idx[(i + 2 < n) ? (i + 2) : (n - 1)];

    // ---- compute step i ----
    const float4* lk4 = (const float4*)&lk[cur][kh * 32];
    const float4* lq4 = (const float4*)&lq[cur][kh * 32];
    float2 myk[16];
    float2 ca = make_float2(0.f, 0.f), cb = ca, cc = ca, cd = ca;
#pragma unroll
    for (int j = 0; j < 8; ++j) {
      const float4 k4 = lk4[j];
      const float2 klo = make_float2(k4.x, k4.y);
      const float2 khi = make_float2(k4.z, k4.w);
      myk[2 * j] = klo; myk[2 * j + 1] = khi;
      if (j & 1) { cc = f2fma(klo, S2[2 * j], cc); cd = f2fma(khi, S2[2 * j + 1], cd); }
      else       { ca = f2fma(klo, S2[2 * j], ca); cb = f2fma(khi, S2[2 * j + 1], cb); }
    }
    const float2 cs = f2add(f2add(ca, cb), f2add(cc, cd));
    float c = cs.x + cs.y;
    c += __shfl_xor(c, 32);  // combine k-halves: both halves now hold full dot

    const float delta = (vv - egc * c) * bt;
    const float2 d2 = make_float2(delta, delta);
    const float2 eg2 = make_float2(egc, egc);
    float2 oa = make_float2(0.f, 0.f), ob = oa, oc = oa, od = oa;
#pragma unroll
    for (int j = 0; j < 8; ++j) {
      const float4 q4 = lq4[j];
      const float2 qlo = make_float2(q4.x, q4.y);
      const float2 qhi = make_float2(q4.z, q4.w);
      const float2 s0 = f2fma(S2[2 * j], eg2, f2mul(myk[2 * j], d2));
      const float2 s1 = f2fma(S2[2 * j + 1], eg2, f2mul(myk[2 * j + 1], d2));
      S2[2 * j] = s0; S2[2 * j + 1] = s1;
      if (j & 1) { oc = f2fma(qlo, s0, oc); od = f2fma(qhi, s1, od); }
      else       { oa = f2fma(qlo, s0, oa); ob = f2fma(qhi, s1, ob); }
    }
    const float2 os = f2add(f2add(oa, ob), f2add(oc, od));
    float o = os.x + os.y;
    o += __shfl_xor(o, 32);
    if (kh == 0)
      atomicAdd(&coreb[(size_t)t_cur * DMODEL + hh * 64 + cv], o * 0.125f * we);

    // ---- stage step i+1 (loads have had the whole compute phase to land) ----
    lk[nxt][lane] = kreg_n;
    lq[nxt][lane] = qreg_n;
    vv = vv_n;
    egc = expf(gv_n);
    bt = bt_n;
    we = we_n;
    t_cur = tn;
    l_nxt = l_nn;
  }
}

// ---------------- fused gated RMSNorm: one wave per (token, head) ----------------
__global__ __launch_bounds__(512) void rmsnorm_kernel(
    const float* __restrict__ coreb, const float* __restrict__ gateb,
    const float* __restrict__ wn, float* __restrict__ outb) {
  const int t = blockIdx.x;
  const int tid = threadIdx.x;  // 512 = 8 heads * 64; wave == head
  const int v = tid & 63;
  const float x = coreb[(size_t)t * DMODEL + tid];
  float ss = x * x;
#pragma unroll
  for (int off = 1; off < 64; off <<= 1) ss += __shfl_xor(ss, off);
  const float r = rsqrtf(ss * (1.0f / 64.0f) + 1e-5f);
  const float gt = gateb[(size_t)t * DMODEL + tid];  // already silu'd
  outb[(size_t)t * DMODEL + tid] = x * r * wn[v] * gt;
}

extern "C" void kernel_launch(void* const* d_in, const int* in_sizes, int n_in,
                              void* d_out, int out_size, void* d_ws, size_t ws_size,
                              hipStream_t stream) {
  const float* h       = (const float*)d_in[0];
  const float* Wq      = (const float*)d_in[1];
  const float* Wgate   = (const float*)d_in[2];
  const float* Wk      = (const float*)d_in[3];
  const float* Wv      = (const float*)d_in[4];
  const float* Wb      = (const float*)d_in[5];
  const float* Wa      = (const float*)d_in[6];
  const float* A_log   = (const float*)d_in[7];
  const float* dt_bias = (const float*)d_in[8];
  const float* Wg      = (const float*)d_in[9];
  const float* wn      = (const float*)d_in[10];
  const float* Wo      = (const float*)d_in[11];
  float* out = (float*)d_out;

  float* ws = (float*)d_ws;
  const size_t big = (size_t)NTOK * DMODEL;  // 2M floats
  float* qb    = ws;
  float* kb    = qb + big;
  float* vb    = kb + big;
  float* gateb = vb + big;
  float* coreb = gateb + big;
  float* betab = coreb + big;
  float* gbuf  = betab + (size_t)NTOK * NHEADS;
  float* wbuf  = gbuf + (size_t)NTOK * NHEADS;
  int*   tidx  = (int*)(wbuf + (size_t)NTOK * NEXP);
  int*   tcnt  = tidx + (size_t)NEXP * BATCH * SEQ;
  float* normb = qb;  // reuse q buffer after the scan

  // zero the core accumulator (ws is poisoned before every timed launch)
  zero_kernel<<<dim3(NTOK * DMODEL / 4 / 256), 256, 0, stream>>>((float4*)coreb);

  router_kernel<<<dim3(NTOK), 64, 0, stream>>>(h, Wb, Wa, Wgate, A_log, dt_bias,
                                               betab, gbuf, wbuf);

  compact_kernel<<<dim3(NEXP, BATCH), 64, 0, stream>>>(wbuf, tidx, tcnt);

  dim3 gg(NTOK / 64, DMODEL / 64);
  gemm512<2><<<gg, 256, 0, stream>>>(h, Wq, qb);
  gemm512<2><<<gg, 256, 0, stream>>>(h, Wk, kb);
  gemm512<1><<<gg, 256, 0, stream>>>(h, Wv, vb);
  gemm512<1><<<gg, 256, 0, stream>>>(h, Wg, gateb);

  scan_kernel<<<dim3(NEXP * 2, BATCH, NHEADS), 64, 0, stream>>>(
      qb, kb, vb, betab, gbuf, wbuf, tidx, tcnt, coreb);

  rmsnorm_kernel<<<dim3(NTOK), 512, 0, stream>>>(coreb, gateb, wn, normb);

  gemm512<0><<<gg, 256, 0, stream>>>(normb, Wo, out);
}

// Round 3
// 572.641 us; speedup vs baseline: 1.6208x; 1.3025x over previous
//
#include <hip/hip_runtime.h>
#include <math.h>

#define DMODEL 512
#define NHEADS 8
#define NEXP 4
#define SEQ 1024
#define BATCH 4
#define NTOK 4096  // BATCH * SEQ

typedef float v2f __attribute__((ext_vector_type(2)));
typedef float v4f __attribute__((ext_vector_type(4)));

__device__ __forceinline__ float dev_sigmoid(float x) { return 1.0f / (1.0f + expf(-x)); }
__device__ __forceinline__ float dev_silu(float x) { return x / (1.0f + expf(-x)); }
__device__ __forceinline__ float dev_softplus(float x) {
  return x > 0.0f ? x + log1pf(expf(-x)) : log1pf(expf(x));
}

// ---------------- zero kernel (core accumulator must start at 0; ws is poisoned 0xAA) ----
__global__ __launch_bounds__(256) void zero_kernel(float4* __restrict__ p) {
  p[(size_t)blockIdx.x * 256 + threadIdx.x] = make_float4(0.f, 0.f, 0.f, 0.f);
}

// ---------------- router + beta/g small projections: one wave per token ----------------
__global__ __launch_bounds__(64) void router_kernel(
    const float* __restrict__ h, const float* __restrict__ Wb,
    const float* __restrict__ Wa, const float* __restrict__ Wgate,
    const float* __restrict__ A_log, const float* __restrict__ dt_bias,
    float* __restrict__ beta_o, float* __restrict__ g_o, float* __restrict__ w_o) {
  const int t = blockIdx.x;
  const int lane = threadIdx.x;
  float hv[8];
#pragma unroll
  for (int j = 0; j < 8; ++j) hv[j] = h[(size_t)t * DMODEL + j * 64 + lane];
  float db[8], da[8], dg[4];
#pragma unroll
  for (int c = 0; c < 8; ++c) {
    float s1 = 0.f, s2 = 0.f;
#pragma unroll
    for (int j = 0; j < 8; ++j) {
      int row = j * 64 + lane;
      s1 += hv[j] * Wb[row * NHEADS + c];
      s2 += hv[j] * Wa[row * NHEADS + c];
    }
#pragma unroll
    for (int off = 1; off < 64; off <<= 1) {
      s1 += __shfl_xor(s1, off);
      s2 += __shfl_xor(s2, off);
    }
    db[c] = s1; da[c] = s2;
  }
#pragma unroll
  for (int c = 0; c < 4; ++c) {
    float s = 0.f;
#pragma unroll
    for (int j = 0; j < 8; ++j) s += hv[j] * Wgate[(j * 64 + lane) * NEXP + c];
#pragma unroll
    for (int off = 1; off < 64; off <<= 1) s += __shfl_xor(s, off);
    dg[c] = s;
  }
  if (lane == 0) {
#pragma unroll
    for (int c = 0; c < 8; ++c) {
      beta_o[t * NHEADS + c] = dev_sigmoid(db[c]);
      g_o[t * NHEADS + c] = -expf(A_log[c]) * dev_softplus(da[c] + dt_bias[c]);
    }
    // softmax over 4 experts (max-subtracted, like jax.nn.softmax)
    float mx = fmaxf(fmaxf(dg[0], dg[1]), fmaxf(dg[2], dg[3]));
    float p[4]; float sum = 0.f;
#pragma unroll
    for (int c = 0; c < 4; ++c) { p[c] = expf(dg[c] - mx); sum += p[c]; }
#pragma unroll
    for (int c = 0; c < 4; ++c) p[c] /= sum;
    // top-2, first-occurrence tie-break (matches jax.lax.top_k)
    float v1 = -1e30f; int i1 = 0;
#pragma unroll
    for (int c = 0; c < 4; ++c) { if (p[c] > v1) { v1 = p[c]; i1 = c; } }
    float v2 = -1e30f; int i2 = -1;
#pragma unroll
    for (int c = 0; c < 4; ++c) { if (c != i1 && p[c] > v2) { v2 = p[c]; i2 = c; } }
    float s2v = v1 + v2;
#pragma unroll
    for (int c = 0; c < 4; ++c) {
      float wv = 0.f;
      if (c == i1) wv = v1 / s2v;
      else if (c == i2) wv = v2 / s2v;
      w_o[t * NEXP + c] = wv;
    }
  }
}

// ---------------- routed-token compaction: one wave per (e,b) ----------------
__global__ __launch_bounds__(64) void compact_kernel(
    const float* __restrict__ wbuf, int* __restrict__ tidx, int* __restrict__ tcnt) {
  const int e = blockIdx.x, b = blockIdx.y;
  const int lane = threadIdx.x;
  int* out = tidx + (e * BATCH + b) * SEQ;
  int cnt = 0;
  for (int g0 = 0; g0 < SEQ; g0 += 64) {
    const int l = g0 + lane;
    const float w = wbuf[(b * SEQ + l) * NEXP + e];
    const unsigned long long m = __ballot(w > 0.f);
    const int pos = __popcll(m & ((1ull << lane) - 1ull));
    if (w > 0.f) out[cnt + pos] = l;
    cnt += __popcll(m);
  }
  if (lane == 0) tcnt[e * BATCH + b] = cnt;
}

// ---------------- fp32 tiled GEMM: C[M,512] = A[M,512] @ B[512,512] -----------------
// MODE 0: plain   MODE 1: silu   MODE 2: silu + per-64-col-head l2norm
template <int MODE>
__global__ __launch_bounds__(256) void gemm512(
    const float* __restrict__ A, const float* __restrict__ B,
    float* __restrict__ C) {
  constexpr int N = DMODEL, K = DMODEL;
  __shared__ float As[32][68];  // [k][m], padded
  __shared__ float Bs[32][68];  // [k][n], padded
  const int tid = threadIdx.x;
  const int tx = tid & 15, ty = tid >> 4;
  const int m0 = blockIdx.x * 64, n0 = blockIdx.y * 64;
  const int ar = tid >> 3, ak = (tid & 7) * 4;
  const int bk = tid >> 4, bn = (tid & 15) * 4;
  float acc[4][4] = {};
  for (int kk = 0; kk < K; kk += 32) {
    float4 a0 = *(const float4*)&A[(size_t)(m0 + ar) * K + kk + ak];
    float4 a1 = *(const float4*)&A[(size_t)(m0 + ar + 32) * K + kk + ak];
    float4 b0 = *(const float4*)&B[(size_t)(kk + bk) * N + n0 + bn];
    float4 b1 = *(const float4*)&B[(size_t)(kk + bk + 16) * N + n0 + bn];
    __syncthreads();
    As[ak + 0][ar] = a0.x; As[ak + 1][ar] = a0.y; As[ak + 2][ar] = a0.z; As[ak + 3][ar] = a0.w;
    As[ak + 0][ar + 32] = a1.x; As[ak + 1][ar + 32] = a1.y; As[ak + 2][ar + 32] = a1.z; As[ak + 3][ar + 32] = a1.w;
    *(float4*)&Bs[bk][bn] = b0;
    *(float4*)&Bs[bk + 16][bn] = b1;
    __syncthreads();
#pragma unroll
    for (int kq = 0; kq < 32; ++kq) {
      float4 a4 = *(const float4*)&As[kq][ty * 4];
      float4 b4 = *(const float4*)&Bs[kq][tx * 4];
      float av[4] = {a4.x, a4.y, a4.z, a4.w};
      float bv[4] = {b4.x, b4.y, b4.z, b4.w};
#pragma unroll
      for (int i = 0; i < 4; ++i)
#pragma unroll
        for (int j = 0; j < 4; ++j) acc[i][j] = fmaf(av[i], bv[j], acc[i][j]);
    }
  }
  if (MODE == 0) {
#pragma unroll
    for (int i = 0; i < 4; ++i) {
      float4 v4 = make_float4(acc[i][0], acc[i][1], acc[i][2], acc[i][3]);
      *(float4*)&C[(size_t)(m0 + ty * 4 + i) * N + n0 + tx * 4] = v4;
    }
  } else {
    float s[4][4];
#pragma unroll
    for (int i = 0; i < 4; ++i)
#pragma unroll
      for (int j = 0; j < 4; ++j) s[i][j] = dev_silu(acc[i][j]);
    if (MODE == 2) {
      // l2norm over the 64 cols of this head (tile == head): reduce across the 16 tx lanes
      float ss[4];
#pragma unroll
      for (int i = 0; i < 4; ++i)
        ss[i] = s[i][0] * s[i][0] + s[i][1] * s[i][1] + s[i][2] * s[i][2] + s[i][3] * s[i][3];
#pragma unroll
      for (int off = 1; off < 16; off <<= 1) {
#pragma unroll
        for (int i = 0; i < 4; ++i) ss[i] += __shfl_xor(ss[i], off);
      }
#pragma unroll
      for (int i = 0; i < 4; ++i) {
        float rn = 1.0f / sqrtf(ss[i] + 1e-6f);
#pragma unroll
        for (int j = 0; j < 4; ++j) s[i][j] *= rn;
      }
    }
#pragma unroll
    for (int i = 0; i < 4; ++i) {
      float4 v4 = make_float4(s[i][0], s[i][1], s[i][2], s[i][3]);
      *(float4*)&C[(size_t)(m0 + ty * 4 + i) * N + n0 + tx * 4] = v4;
    }
  }
}

// ---------------- gated delta-rule scan ----------------
// grid (NEXP*2, BATCH, NHEADS); ONE WAVE per block (no __syncthreads in loop;
// DS ops are in-order within a wave, wave_barrier pins compiler ordering).
// vhalf = blockIdx.x&1 selects 32 of the 64 v-columns; lane = (kh, vi):
// kh = lane>>5 picks the k-half, vi = lane&31 the v-column.
// Depth-3 software pipeline, rotating mod-4 register slots:
//   iter s: issue global loads for step s+3; ds_read token for step s+4;
//           stage LDS (4 buffers) for step s+1; compute step s.
__global__ __launch_bounds__(64) void scan_kernel(
    const float* __restrict__ qb, const float* __restrict__ kb,
    const float* __restrict__ vb, const float* __restrict__ betab,
    const float* __restrict__ gbuf, const float* __restrict__ wbuf,
    const int* __restrict__ tidx, const int* __restrict__ tcnt,
    float* __restrict__ coreb) {
  const int vhalf = blockIdx.x & 1, e = blockIdx.x >> 1;
  const int b = blockIdx.y, hh = blockIdx.z;
  const int lane = threadIdx.x;
  const int kh = lane >> 5;
  const int vi = lane & 31;
  const int cv = vhalf * 32 + vi;
  const int* idx = tidx + (e * BATCH + b) * SEQ;
  const int n = tcnt[e * BATCH + b];
  if (n == 0) return;
  const int nm1 = n - 1;

  __shared__ __align__(16) float lk[4][64];
  __shared__ __align__(16) float lq[4][64];
  __shared__ int lidx[SEQ];

  // preload (clamped) token list into LDS
  for (int i = lane; i < SEQ; i += 64) lidx[i] = idx[i < n ? i : nm1];
  __syncthreads();  // once, outside the hot loop

  v2f S2[16];
#pragma unroll
  for (int j = 0; j < 16; ++j) S2[j] = (v2f){0.f, 0.f};

  float kf[4], qf[4], vf[4], gf[4], bf[4], wf[4], egr[4];
  int tcur[4], tok4[4];

#define PREF(SLOT, TK)                                          \
  do {                                                          \
    const int tn_ = b * SEQ + (TK);                             \
    const size_t kq_ = (size_t)tn_ * DMODEL + hh * 64 + lane;   \
    kf[SLOT] = kb[kq_];                                         \
    qf[SLOT] = qb[kq_];                                         \
    vf[SLOT] = vb[(size_t)tn_ * DMODEL + hh * 64 + cv];         \
    gf[SLOT] = gbuf[tn_ * NHEADS + hh];                         \
    bf[SLOT] = betab[tn_ * NHEADS + hh];                        \
    wf[SLOT] = wbuf[tn_ * NEXP + e];                            \
    tcur[SLOT] = tn_;                                           \
  } while (0)

  // prologue: tokens for steps 0..3; loads for steps 0..2; stage step 0
  tok4[0] = lidx[0];
  tok4[1] = lidx[1 < n ? 1 : nm1];
  tok4[2] = lidx[2 < n ? 2 : nm1];
  tok4[3] = lidx[3 < n ? 3 : nm1];
  PREF(0, tok4[0]);
  PREF(1, tok4[1]);
  PREF(2, tok4[2]);
  lk[0][lane] = kf[0];
  lq[0][lane] = qf[0];
  egr[0] = expf(gf[0]);

  const int m = (n + 3) & ~3;
  for (int i = 0; i < m; i += 4) {
#pragma unroll
    for (int u = 0; u < 4; ++u) {
      const int s = i + u;
      const int sN = (u + 3) & 3;  // slot of step s+3 (prefetch target)
      const int s1 = (u + 1) & 3;  // slot of step s+1 (LDS stage)
      // 1. issue global loads for step s+3 (token ds_read one iter ago)
      PREF(sN, tok4[sN]);
      // 2. ds_read token for step s+4 (consumed next iteration)
      int a4 = s + 4;
      a4 = a4 < nm1 ? a4 : nm1;
      tok4[u] = lidx[a4];
      // 3. stage LDS for step s+1 from regs loaded 3 iterations ago
      __builtin_amdgcn_wave_barrier();
      lk[s1][lane] = kf[s1];
      lq[s1][lane] = qf[s1];
      __builtin_amdgcn_wave_barrier();
      egr[s1] = expf(gf[s1]);
      // 4. compute step s from LDS slot u (staged last iteration)
      const v4f* lk4 = (const v4f*)&lk[u][kh * 32];
      const v4f* lq4 = (const v4f*)&lq[u][kh * 32];
      v2f myk[16];
      v2f c0 = (v2f){0.f, 0.f}, c1 = c0, c2 = c0, c3 = c0;
#pragma unroll
      for (int j = 0; j < 8; ++j) {
        const v4f k4 = lk4[j];
        const v2f klo = (v2f){k4.x, k4.y};
        const v2f khi = (v2f){k4.z, k4.w};
        myk[2 * j] = klo; myk[2 * j + 1] = khi;
        if (j & 1) {
          c2 = __builtin_elementwise_fma(klo, S2[2 * j], c2);
          c3 = __builtin_elementwise_fma(khi, S2[2 * j + 1], c3);
        } else {
          c0 = __builtin_elementwise_fma(klo, S2[2 * j], c0);
          c1 = __builtin_elementwise_fma(khi, S2[2 * j + 1], c1);
        }
      }
      const v2f cacc = (c0 + c1) + (c2 + c3);
      float c = cacc.x + cacc.y;
      c += __shfl_xor(c, 32);  // combine k-halves
      const float egc = egr[u];
      const float delta = (vf[u] - egc * c) * bf[u];
      const v2f d2 = (v2f){delta, delta};
      const v2f eg2 = (v2f){egc, egc};
      v2f o0 = (v2f){0.f, 0.f}, o1 = o0, o2 = o0, o3 = o0;
#pragma unroll
      for (int j = 0; j < 8; ++j) {
        const v4f q4 = lq4[j];
        const v2f qlo = (v2f){q4.x, q4.y};
        const v2f qhi = (v2f){q4.z, q4.w};
        const v2f s0 = __builtin_elementwise_fma(S2[2 * j], eg2, myk[2 * j] * d2);
        const v2f s1v = __builtin_elementwise_fma(S2[2 * j + 1], eg2, myk[2 * j + 1] * d2);
        S2[2 * j] = s0; S2[2 * j + 1] = s1v;
        if (j & 1) {
          o2 = __builtin_elementwise_fma(qlo, s0, o2);
          o3 = __builtin_elementwise_fma(qhi, s1v, o3);
        } else {
          o0 = __builtin_elementwise_fma(qlo, s0, o0);
          o1 = __builtin_elementwise_fma(qhi, s1v, o1);
        }
      }
      const v2f oacc = (o0 + o1) + (o2 + o3);
      float o = oacc.x + oacc.y;
      o += __shfl_xor(o, 32);
      if (kh == 0 && s < n)
        atomicAdd(&coreb[(size_t)tcur[u] * DMODEL + hh * 64 + cv],
                  o * 0.125f * wf[u]);
    }
  }
#undef PREF
}

// ---------------- fused gated RMSNorm: one wave per (token, head) ----------------
__global__ __launch_bounds__(512) void rmsnorm_kernel(
    const float* __restrict__ coreb, const float* __restrict__ gateb,
    const float* __restrict__ wn, float* __restrict__ outb) {
  const int t = blockIdx.x;
  const int tid = threadIdx.x;  // 512 = 8 heads * 64; wave == head
  const int v = tid & 63;
  const float x = coreb[(size_t)t * DMODEL + tid];
  float ss = x * x;
#pragma unroll
  for (int off = 1; off < 64; off <<= 1) ss += __shfl_xor(ss, off);
  const float r = rsqrtf(ss * (1.0f / 64.0f) + 1e-5f);
  const float gt = gateb[(size_t)t * DMODEL + tid];  // already silu'd
  outb[(size_t)t * DMODEL + tid] = x * r * wn[v] * gt;
}

extern "C" void kernel_launch(void* const* d_in, const int* in_sizes, int n_in,
                              void* d_out, int out_size, void* d_ws, size_t ws_size,
                              hipStream_t stream) {
  const float* h       = (const float*)d_in[0];
  const float* Wq      = (const float*)d_in[1];
  const float* Wgate   = (const float*)d_in[2];
  const float* Wk      = (const float*)d_in[3];
  const float* Wv      = (const float*)d_in[4];
  const float* Wb      = (const float*)d_in[5];
  const float* Wa      = (const float*)d_in[6];
  const float* A_log   = (const float*)d_in[7];
  const float* dt_bias = (const float*)d_in[8];
  const float* Wg      = (const float*)d_in[9];
  const float* wn      = (const float*)d_in[10];
  const float* Wo      = (const float*)d_in[11];
  float* out = (float*)d_out;

  float* ws = (float*)d_ws;
  const size_t big = (size_t)NTOK * DMODEL;  // 2M floats
  float* qb    = ws;
  float* kb    = qb + big;
  float* vb    = kb + big;
  float* gateb = vb + big;
  float* coreb = gateb + big;
  float* betab = coreb + big;
  float* gbuf  = betab + (size_t)NTOK * NHEADS;
  float* wbuf  = gbuf + (size_t)NTOK * NHEADS;
  int*   tidx  = (int*)(wbuf + (size_t)NTOK * NEXP);
  int*   tcnt  = tidx + (size_t)NEXP * BATCH * SEQ;
  float* normb = qb;  // reuse q buffer after the scan

  // zero the core accumulator (ws is poisoned before every timed launch)
  zero_kernel<<<dim3(NTOK * DMODEL / 4 / 256), 256, 0, stream>>>((float4*)coreb);

  router_kernel<<<dim3(NTOK), 64, 0, stream>>>(h, Wb, Wa, Wgate, A_log, dt_bias,
                                               betab, gbuf, wbuf);

  compact_kernel<<<dim3(NEXP, BATCH), 64, 0, stream>>>(wbuf, tidx, tcnt);

  dim3 gg(NTOK / 64, DMODEL / 64);
  gemm512<2><<<gg, 256, 0, stream>>>(h, Wq, qb);
  gemm512<2><<<gg, 256, 0, stream>>>(h, Wk, kb);
  gemm512<1><<<gg, 256, 0, stream>>>(h, Wv, vb);
  gemm512<1><<<gg, 256, 0, stream>>>(h, Wg, gateb);

  scan_kernel<<<dim3(NEXP * 2, BATCH, NHEADS), 64, 0, stream>>>(
      qb, kb, vb, betab, gbuf, wbuf, tidx, tcnt, coreb);

  rmsnorm_kernel<<<dim3(NTOK), 512, 0, stream>>>(coreb, gateb, wn, normb);

  gemm512<0><<<gg, 256, 0, stream>>>(normb, Wo, out);
}